// Round 11
// baseline (355.327 us; speedup 1.0000x reference)
//
#include <hip/hip_runtime.h>
#include <math.h>

#define Bn 64
#define Qn 1000
#define Dn 512
#define Cn 81
#define NK 80
#define KB 5
#define MK 5
#define DELTA_T 0.6f
#define FILT_T 0.55f
#define INV_TAU 10.0f
#define NROWS (Bn*Qn)
#define NBK (Bn*NK)
#define NBD 448
#define CAND_CAP 65024

typedef short bf16x8 __attribute__((ext_vector_type(8)));
typedef float f32x4v __attribute__((ext_vector_type(4)));

// Permuted bf16 layout: row r, chunk (s in 0..15, quad in 0..3) holding
// d = quad*8 + s*32 .. +8  lives at elem offset (r>>4)*8192 + s*512 + ((quad*16)+(r&15))*8.
// A wave's MFMA fragment load (16-row tile, all quads, fixed s) is a contiguous 1KB load.

__device__ inline float d4f(const float4 a, const float4 b){
  return a.x*b.x + a.y*b.y + a.z*b.z + a.w*b.w;
}
__device__ inline float wred(float v){
  #pragma unroll
  for (int o = 32; o; o >>= 1) v += __shfl_xor(v, o, 64);
  return v;
}
__device__ inline int wredi(int v){
  #pragma unroll
  for (int o = 32; o; o >>= 1) v += __shfl_xor(v, o, 64);
  return v;
}
__device__ inline unsigned short f2bf(float x){
  union{float f; unsigned u;} v; v.f = x;
  unsigned r = v.u + 0x7fff + ((v.u >> 16) & 1);
  return (unsigned short)(r >> 16);
}
__device__ inline float dot512(const float* __restrict__ a, const float* __restrict__ b){
  const float4* A = (const float4*)a;
  const float4* B = (const float4*)b;
  float s = 0.f;
  for (int i = 0; i < 128; i++) s += d4f(A[i], B[i]);
  return s;
}

// K0: block per proto row. proton fp32; protonb bf16 PERMUTED (rows 81..95 zeroed); proto_sq = ||p_c||^2.
__global__ __launch_bounds__(256) void k_proto(const float* __restrict__ protos,
    float* __restrict__ proton, unsigned short* __restrict__ protonb,
    float* __restrict__ proto_sq, int write_pb){
  int c = blockIdx.x, tid = threadIdx.x;
  int sP = tid >> 4;
  int quadP = (tid & 15) >> 2;
  int offP = (2*tid) & 7;
  size_t pb = (size_t)(c >> 4)*8192 + (size_t)sP*512 + (size_t)(quadP*16 + (c & 15))*8 + offP;
  if (c >= Cn){
    if (write_pb) *(unsigned int*)(protonb + pb) = 0u;
    return;
  }
  __shared__ float accw[4];
  float2 x = ((const float2*)(protos + (size_t)c*Dn))[tid];
  float ss = wred(x.x*x.x + x.y*x.y);
  int wid = tid >> 6, lane = tid & 63;
  if (lane == 0) accw[wid] = ss;
  __syncthreads();
  float s = accw[0] + accw[1] + accw[2] + accw[3];
  float inv = 1.0f / fmaxf(sqrtf(s), 1e-12f);
  float2 y; y.x = x.x*inv; y.y = x.y*inv;
  ((float2*)(proton + (size_t)c*Dn))[tid] = y;
  if (tid == 0) proto_sq[c] = s;
  if (write_pb){
    unsigned int pk = ((unsigned)f2bf(y.y) << 16) | (unsigned)f2bf(y.x);
    *(unsigned int*)(protonb + pb) = pk;
  }
}

// K1: block = one 16-row embn tile; swizzled LDS transpose; coalesced tile write.
__global__ __launch_bounds__(256) void k_row(const float* __restrict__ embs,
    const float* __restrict__ protos, const float* __restrict__ proto_sq,
    const int* __restrict__ labels, float* __restrict__ inv_norm,
    float* __restrict__ dist, unsigned short* __restrict__ embn, int write_e){
  __shared__ bf16x8 T[1024];   // 16 KB
  int tid = threadIdx.x, w = tid >> 6, lane = tid & 63;
  int r0 = blockIdx.x*16;
  char* base = (char*)T;
  #pragma unroll
  for (int i = 0; i < 4; i++){
    int j = w*4 + i;
    int row = r0 + j;
    const float4* e = (const float4*)(embs + (size_t)row*Dn);
    float4 a = e[lane], b = e[lane+64];
    int lab = labels[row];                      // wave-uniform
    float e2 = wred(d4f(a,a) + d4f(b,b));
    float ep = 0.f;
    if (lab < NK){
      const float4* p = (const float4*)(protos + (size_t)lab*Dn);
      ep = wred(d4f(a, p[lane]) + d4f(b, p[lane+64]));
    }
    float inv = 1.0f / fmaxf(sqrtf(e2), 1e-12f);
    if (lane == 0){
      inv_norm[row] = inv;
      dist[row] = (lab < NK) ? sqrtf(fmaxf(e2 - 2.f*ep + proto_sq[lab], 1e-12f)) : -INFINITY;
    }
    if (write_e){
      ushort4 ua; ua.x=f2bf(a.x*inv); ua.y=f2bf(a.y*inv); ua.z=f2bf(a.z*inv); ua.w=f2bf(a.w*inv);
      ushort4 ub; ub.x=f2bf(b.x*inv); ub.y=f2bf(b.y*inv); ub.z=f2bf(b.z*inv); ub.w=f2bf(b.w*inv);
      int g  = lane >> 1;
      int off = (lane & 1) * 8;
      *(ushort4*)(base + g*256       + (((j + g)      & 15) << 4) + off) = ua;
      *(ushort4*)(base + (g+32)*256  + (((j + g + 32) & 15) << 4) + off) = ub;
    }
  }
  if (write_e){
    __syncthreads();
    unsigned short* out = embn + (size_t)(r0 >> 4)*8192;
    #pragma unroll
    for (int pp = 0; pp < 4; pp++){
      int c = tid + pp*256;
      int g = c >> 4, j = c & 15;
      bf16x8 v = *(bf16x8*)(base + g*256 + (((j + g) & 15) << 4));
      *(bf16x8*)(out + (size_t)c*8) = v;
    }
  }
}

// K3: wave per (b,k). Invalid boundary slots get bd_row = -1.
__global__ __launch_bounds__(256) void k_top5(const int* __restrict__ labels,
    const float* __restrict__ dist, int* __restrict__ topi, int* __restrict__ nmatch,
    int* __restrict__ bd_row, int write_bd){
  int wid = threadIdx.x >> 6, lane = threadIdx.x & 63;
  int gid = blockIdx.x*4 + wid;
  if (gid >= NBK) return;
  int b = gid / NK, k = gid - b*NK;
  const int*   lrow = labels + b*Qn;
  const float* drow = dist   + b*Qn;
  float v[KB]; int id[KB];
  #pragma unroll
  for (int j = 0; j < KB; j++){ v[j] = -INFINITY; id[j] = 0x7fffffff; }
  int cnt = 0;
  for (int q = lane; q < Qn; q += 64){
    if (lrow[q] == k){
      cnt++;
      float nv = drow[q]; int ni = q;
      #pragma unroll
      for (int j = 0; j < KB; j++){
        bool better = (nv > v[j]) || (nv == v[j] && ni < id[j]);
        if (better){
          float tv = v[j]; v[j] = nv; nv = tv;
          int ti = id[j]; id[j] = ni; ni = ti;
        }
      }
    }
  }
  cnt = wredi(cnt);
  int p = 0;
  int outi[KB];
  #pragma unroll
  for (int s = 0; s < KB; s++){
    float bv = (p < KB) ? v[p] : -INFINITY;
    int   bi = (p < KB) ? id[p] : 0x7fffffff;
    int   bl = lane;
    #pragma unroll
    for (int o = 32; o; o >>= 1){
      float ov = __shfl_xor(bv, o, 64);
      int   oi = __shfl_xor(bi, o, 64);
      int   ol = __shfl_xor(bl, o, 64);
      if (ov > bv || (ov == bv && oi < bi)){ bv = ov; bi = oi; bl = ol; }
    }
    if (bl == lane) p++;
    outi[s] = (bv != -INFINITY) ? bi : 0;
  }
  if (lane == 0){
    #pragma unroll
    for (int j = 0; j < KB; j++) topi[gid*KB + j] = outi[j];
    nmatch[gid] = cnt;
    if (write_bd){
      int cv = cnt < KB ? cnt : KB;
      #pragma unroll
      for (int j = 0; j < KB; j++)
        bd_row[b*NBD + k*KB + j] = (j < cv) ? (b*Qn + outi[j]) : -1;
      if (k < NBD - NK*KB) bd_row[b*NBD + NK*KB + k] = -1;
    }
  }
}

// K2b: CEC via MFMA on permuted layout (coalesced A and B frag loads).
__global__ __launch_bounds__(256) void k_cec_mfma(
    const unsigned short* __restrict__ embn, const unsigned short* __restrict__ protonb,
    const int* __restrict__ labels, float* __restrict__ pos_exp,
    float* __restrict__ col_sum, float* __restrict__ pos_sum){
  __shared__ float colL[96], posL[96];
  int tid = threadIdx.x, w = tid >> 6, l = tid & 63;
  for (int i = tid; i < 96; i += 256){ colL[i] = 0.f; posL[i] = 0.f; }
  __syncthreads();
  int quad = l >> 4, m15 = l & 15;
  int r0 = blockIdx.x*64 + w*16;
  const unsigned short* abase = embn + (size_t)(r0 >> 4)*8192 + (size_t)l*8;
  const unsigned short* bbase = protonb + (size_t)l*8;
  f32x4v acc[6];
  #pragma unroll
  for (int f = 0; f < 6; f++) acc[f] = (f32x4v){0.f,0.f,0.f,0.f};
  for (int s = 0; s < 16; s++){
    bf16x8 a = *(const bf16x8*)(abase + s*512);
    #pragma unroll
    for (int f = 0; f < 6; f++){
      bf16x8 bb = *(const bf16x8*)(bbase + (size_t)f*8192 + s*512);
      acc[f] = __builtin_amdgcn_mfma_f32_16x16x32_bf16(a, bb, acc[f], 0, 0, 0);
    }
  }
  int labs[4];
  #pragma unroll
  for (int r = 0; r < 4; r++) labs[r] = labels[r0 + quad*4 + r];
  #pragma unroll
  for (int f = 0; f < 6; f++){
    int c = f*16 + m15;
    float colp = 0.f;
    #pragma unroll
    for (int r = 0; r < 4; r++){
      if (labs[r] < NK && c < Cn){
        float es = expf(acc[f][r] * INV_TAU);
        colp += es;
        if (labs[r] == c){
          pos_exp[r0 + quad*4 + r] = es;
          atomicAdd(&posL[c], es);
        }
      }
    }
    colp += __shfl_xor(colp, 16, 64);
    colp += __shfl_xor(colp, 32, 64);
    if (quad == 0 && c < Cn && colp != 0.f) atomicAdd(&colL[c], colp);
  }
  __syncthreads();
  for (int i = tid; i < Cn; i += 256){
    if (colL[i] != 0.f) atomicAdd(&col_sum[i], colL[i]);
    if (posL[i] != 0.f) atomicAdd(&pos_sum[i], posL[i]);
  }
}

// K4b v8: LDS dbuf A-tile pipeline; each wave holds TWO B-frag sets (32 n rows)
// so each staged LDS A-read feeds 2 MFMAs (half the LDS traffic, 2 indep chains).
// Grid (b, half, nt) = (64,2,4); block covers 128 n.
__global__ __launch_bounds__(256) void k_sim(
    const unsigned short* __restrict__ embn, const int* __restrict__ bd_row,
    const int* __restrict__ labels, int* __restrict__ cand, int* __restrict__ cand_cnt){
  __shared__ bf16x8 At[2][1024];
  int b = blockIdx.x, half = blockIdx.y, nt = blockIdx.z;
  int tid = threadIdx.x, w = tid >> 6, l = tid & 63;
  int quad = l >> 4, m15 = l & 15;

  int n0 = nt*128 + w*16 + m15;
  int n1 = n0 + 64;
  int i0 = n0 < NBD ? n0 : NBD-1;
  int i1 = n1 < NBD ? n1 : NBD-1;
  int br0 = bd_row[b*NBD + i0];
  int br1 = bd_row[b*NBD + i1];
  int valid0 = (br0 >= 0) && (n0 < NK*KB);
  int valid1 = (br1 >= 0) && (n1 < NK*KB);
  int rowb0 = valid0 ? br0 : b*Qn;
  int rowb1 = valid1 ? br1 : b*Qn;
  const unsigned short* bp0 = embn + (size_t)(rowb0 >> 4)*8192 + (size_t)(rowb0 & 15)*8 + quad*128;
  const unsigned short* bp1 = embn + (size_t)(rowb1 >> 4)*8192 + (size_t)(rowb1 & 15)*8 + quad*128;
  bf16x8 bfr0[16], bfr1[16];
  #pragma unroll
  for (int s = 0; s < 16; s++){
    bfr0[s] = *(const bf16x8*)(bp0 + s*512);
    bfr1[s] = *(const bf16x8*)(bp1 + s*512);
  }

  const int qlo = half*500, qhi = qlo + 500;
  const int bq = b*Qn;
  const int qstart = half ? 488 : 0;

  int jloc = tid & 15, quadp = (tid >> 4) & 3;

  {
    int g = bq + qstart + jloc;
    size_t ro = (size_t)(g >> 4)*8192 + (size_t)(quadp*16 + (g & 15))*8;
    #pragma unroll
    for (int pp = 0; pp < 4; pp++)
      At[0][tid + pp*256] = *(const bf16x8*)(embn + ro + (size_t)(w + pp*4)*512);
  }
  __syncthreads();

  for (int it = 0; it < 32; it++){
    int buf = it & 1;
    bf16x8 pre[4];
    if (it < 31){
      int g = bq + qstart + (it+1)*16 + jloc;
      size_t ro = (size_t)(g >> 4)*8192 + (size_t)(quadp*16 + (g & 15))*8;
      #pragma unroll
      for (int pp = 0; pp < 4; pp++)
        pre[pp] = *(const bf16x8*)(embn + ro + (size_t)(w + pp*4)*512);
    }
    f32x4v a0 = (f32x4v){0.f,0.f,0.f,0.f};
    f32x4v a1 = (f32x4v){0.f,0.f,0.f,0.f};
    #pragma unroll
    for (int s = 0; s < 16; s++){
      bf16x8 av = At[buf][s*64 + l];
      a0 = __builtin_amdgcn_mfma_f32_16x16x32_bf16(av, bfr0[s], a0, 0, 0, 0);
      a1 = __builtin_amdgcn_mfma_f32_16x16x32_bf16(av, bfr1[s], a1, 0, 0, 0);
    }
    int qb = qstart + it*16 + quad*4;
    #pragma unroll
    for (int j = 0; j < 2; j++){
      f32x4v av = j ? a1 : a0;
      int vj = j ? valid1 : valid0;
      int nj = j ? n1 : n0;
      #pragma unroll
      for (int r = 0; r < 4; r++){
        float sv = av[r];
        int q = qb + r;
        if (vj && sv > FILT_T && q >= qlo && q < qhi){
          if (labels[bq + q] >= NK){
            int idx = atomicAdd(cand_cnt, 1);
            if (idx < CAND_CAP) cand[idx] = ((b*NBD + nj) << 10) | q;
          }
        }
      }
    }
    __syncthreads();
    if (it < 31){
      #pragma unroll
      for (int pp = 0; pp < 4; pp++)
        At[buf^1][tid + pp*256] = pre[pp];
    }
    __syncthreads();
  }
}

// K4c: resolve candidates exactly (rare path).
__global__ __launch_bounds__(256) void k_sel(
    const float* __restrict__ embs, const float* __restrict__ inv_norm,
    const int* __restrict__ labels, const int* __restrict__ topi,
    const int* __restrict__ nmatch, const int* __restrict__ cand,
    const int* __restrict__ cand_cnt, const float* __restrict__ cls_w,
    const float* __restrict__ cls_b, float* __restrict__ sul_sum, int* __restrict__ n_sg){
  int gid = blockIdx.x*256 + threadIdx.x;
  if (gid >= NBK) return;
  int b = gid / NK, k = gid - b*NK;
  int nm = nmatch[gid];
  int nvalid = nm < KB ? nm : KB;
  int nc = *cand_cnt; if (nc > CAND_CAP) nc = CAND_CAP;
  if (nvalid == 0 || nc == 0) return;
  float tv[KB][MK]; int ti[KB][MK]; int tc[KB];
  #pragma unroll
  for (int i = 0; i < KB; i++){
    tc[i] = 0;
    #pragma unroll
    for (int j = 0; j < MK; j++){ tv[i][j] = -INFINITY; ti[i][j] = 0x7fffffff; }
  }
  for (int j = 0; j < nc; j++){
    int code = cand[j];
    int q = code & 1023;
    int t = code >> 10;
    int b2 = t / NBD, n = t - b2*NBD;
    if (b2 != b) continue;
    int k2 = n / KB, i = n - k2*KB;
    if (k2 != k || i >= nvalid) continue;
    int rq = b*Qn + q;
    int rb = b*Qn + topi[gid*KB + i];
    float s = inv_norm[rq]*inv_norm[rb]*dot512(embs + (size_t)rq*Dn, embs + (size_t)rb*Dn);
    if (s > DELTA_T){
      tc[i]++;
      float nv = s; int ni = q;
      #pragma unroll
      for (int jj = 0; jj < MK; jj++){
        float cv = tv[i][jj]; int ci = ti[i][jj];
        bool better = (nv > cv) || (nv == cv && ni < ci);
        if (better){ tv[i][jj] = nv; ti[i][jj] = ni; nv = cv; ni = ci; }
      }
    }
  }
  for (int i = 0; i < nvalid; i++){
    int cc = tc[i] < MK ? tc[i] : MK;
    if (cc == 0) continue;
    int rb = b*Qn + topi[gid*KB + i];
    float sc = 1.0f / (1.0f + (float)cc);
    float m = -INFINITY, ssum = 0.f, lunk = 0.f;
    for (int c = 0; c < Cn; c++){
      const float* wc = cls_w + (size_t)c*Dn;
      float a = dot512(embs + (size_t)rb*Dn, wc);
      for (int nn = 0; nn < cc; nn++)
        a += dot512(embs + (size_t)(b*Qn + ti[i][nn])*Dn, wc);
      float logit = a*sc + cls_b[c];
      if (c == Cn-1) lunk = logit;
      if (logit > m){ ssum = ssum*expf(m - logit) + 1.f; m = logit; }
      else ssum += expf(logit - m);
    }
    float ce = (m + logf(ssum)) - lunk;
    atomicAdd(sul_sum, ce);
    atomicAdd(n_sg, 1);
  }
}

// K5: p_neg — block per class, wave per partner chunk.
__global__ __launch_bounds__(256) void k_pneg(const float* __restrict__ proton,
                                              float* __restrict__ pneg){
  __shared__ float accw[4];
  int c = blockIdx.x;
  int wid = threadIdx.x >> 6, lane = threadIdx.x & 63;
  const float4* crow = (const float4*)(proton + (size_t)c*Dn);
  float4 ca = crow[lane], cb = crow[lane+64];
  float acc = 0.f;
  for (int cp = wid; cp < Cn; cp += 4){
    if (cp == c) continue;
    const float4* prow = (const float4*)(proton + (size_t)cp*Dn);
    float s = wred(d4f(ca, prow[lane]) + d4f(cb, prow[lane+64]));
    acc += expf(s*INV_TAU);
  }
  if (lane == 0) accw[wid] = acc;
  __syncthreads();
  if (threadIdx.x == 0) pneg[c] = accw[0]+accw[1]+accw[2]+accw[3];
}

// K6a: CEC row-loss partial sums (125 blocks x 512 rows).
__global__ __launch_bounds__(256) void k_cecsum(const int* __restrict__ labels,
    const float* __restrict__ pos_exp, const float* __restrict__ col_sum,
    const float* __restrict__ pos_sum, const float* __restrict__ pneg,
    float* __restrict__ cecL, float* __restrict__ cecC){
  __shared__ float E[Cn];
  __shared__ float aw[4], cw[4];
  int tid = threadIdx.x;
  for (int i = tid; i < Cn; i += 256) E[i] = pneg[i] + col_sum[i] - pos_sum[i];
  __syncthreads();
  float part = 0.f; int cm = 0;
  int row0 = blockIdx.x*512;
  #pragma unroll
  for (int rr = 0; rr < 2; rr++){
    int r = row0 + rr*256 + tid;
    int lab = labels[r];
    if (lab < NK){
      float pe = pos_exp[r];
      part += -logf(pe / (pe + E[lab] + 1e-8f));
      cm++;
    }
  }
  part = wred(part); cm = wredi(cm);
  int wid = tid >> 6, lane = tid & 63;
  if (lane == 0){ aw[wid] = part; cw[wid] = (float)cm; }
  __syncthreads();
  if (tid == 0){
    atomicAdd(cecL, aw[0]+aw[1]+aw[2]+aw[3]);
    atomicAdd(cecC, cw[0]+cw[1]+cw[2]+cw[3]);
  }
}

// K6b: finalize
__global__ void k_out(const float* __restrict__ cecL, const float* __restrict__ cecC,
    const float* __restrict__ sul_sum, const int* __restrict__ n_sg,
    float* __restrict__ out){
  if (threadIdx.x == 0){
    float cm = *cecC;
    out[1] = (cm > 0.f) ? (*cecL) / fmaxf(cm, 1.f) : 0.f;
    int ns = *n_sg;
    out[0] = (ns > 0) ? (*sul_sum) / (float)ns : 0.f;
  }
}

// ---------------- fallback (small-ws) kernels ----------------
#define TRK 25
#define TSTR 516
__global__ __launch_bounds__(256) void k_cec(const float* __restrict__ embs,
    const int* __restrict__ labels, const float* __restrict__ inv_norm,
    const float* __restrict__ proton, float* __restrict__ pos_exp,
    float* __restrict__ col_sum, float* __restrict__ pos_sum){
  __shared__ float tile[TRK*TSTR];
  __shared__ float colL[Cn], posL[Cn];
  int tid = threadIdx.x;
  int r0 = blockIdx.x * TRK;
  for (int i = tid; i < Cn; i += 256){ colL[i] = 0.f; posL[i] = 0.f; }
  for (int idx = tid; idx < TRK*128; idx += 256){
    int r = idx >> 7, dd = idx & 127;
    float inv = inv_norm[r0 + r];
    float4 v = ((const float4*)(embs + (size_t)(r0+r)*Dn))[dd];
    v.x*=inv; v.y*=inv; v.z*=inv; v.w*=inv;
    ((float4*)(tile + r*TSTR))[dd] = v;
  }
  __syncthreads();
  for (int item = tid; item < 27*TRK; item += 256){
    int g = item / TRK, r = item - g*TRK;
    int row = r0 + r;
    int lab = labels[row];
    if (lab >= NK) continue;
    int c0 = g*3;
    const float4* t  = (const float4*)(tile + r*TSTR);
    const float4* pa = (const float4*)(proton + (size_t)c0*Dn);
    const float4* pb = (const float4*)(proton + (size_t)(c0+1)*Dn);
    const float4* pc = (const float4*)(proton + (size_t)(c0+2)*Dn);
    float a0=0.f, a1=0.f, a2=0.f;
    for (int dd = 0; dd < 128; dd++){
      float4 v = t[dd];
      a0 += d4f(v, pa[dd]);
      a1 += d4f(v, pb[dd]);
      a2 += d4f(v, pc[dd]);
    }
    float es0 = expf(a0*INV_TAU), es1 = expf(a1*INV_TAU), es2 = expf(a2*INV_TAU);
    atomicAdd(&colL[c0+0], es0);
    atomicAdd(&colL[c0+1], es1);
    atomicAdd(&colL[c0+2], es2);
    if (c0+0 == lab){ pos_exp[row] = es0; atomicAdd(&posL[lab], es0); }
    if (c0+1 == lab){ pos_exp[row] = es1; atomicAdd(&posL[lab], es1); }
    if (c0+2 == lab){ pos_exp[row] = es2; atomicAdd(&posL[lab], es2); }
  }
  __syncthreads();
  for (int i = tid; i < Cn; i += 256){
    if (colL[i] != 0.f) atomicAdd(&col_sum[i], colL[i]);
    if (posL[i] != 0.f) atomicAdd(&pos_sum[i], posL[i]);
  }
}

__global__ __launch_bounds__(256) void k_sul(
    const float* __restrict__ embs, const float* __restrict__ inv_norm,
    const int* __restrict__ labels, const int* __restrict__ topi,
    const int* __restrict__ nmatch, const float* __restrict__ cls_w,
    const float* __restrict__ cls_b, float* __restrict__ sul_sum,
    int* __restrict__ n_sg){
  __shared__ float bnorm[KB][Dn];
  __shared__ float braw[KB][Dn];
  __shared__ float gb[KB][Dn];
  __shared__ float logitsL[KB][Cn];
  __shared__ float wlv[4][KB][MK];
  __shared__ int   wli[4][KB][MK];
  __shared__ int   wlc[4][KB];
  __shared__ int   msel[KB][MK];
  __shared__ int   mcnt[KB];
  __shared__ int   sgany;
  int gid = blockIdx.x;
  int nm = nmatch[gid];
  int nvalid = nm < KB ? nm : KB;
  if (nvalid == 0) return;
  int b = gid / NK;
  int tid = threadIdx.x, wid = tid >> 6, lane = tid & 63;
  for (int t = tid; t < nvalid*128; t += 256){
    int i = t >> 7, dd = t & 127;
    int q = topi[gid*KB + i];
    size_t row = (size_t)b*Qn + q;
    float4 v = ((const float4*)(embs + row*Dn))[dd];
    ((float4*)braw[i])[dd] = v;
    float inv = inv_norm[row];
    v.x*=inv; v.y*=inv; v.z*=inv; v.w*=inv;
    ((float4*)bnorm[i])[dd] = v;
  }
  if (tid < 4*KB) ((int*)wlc)[tid] = 0;
  if (tid < 4*KB*MK){ ((float*)wlv)[tid] = -INFINITY; ((int*)wli)[tid] = 0x7fffffff; }
  if (tid == 0) sgany = 0;
  __syncthreads();
  for (int q = wid; q < Qn; q += 4){
    int row = b*Qn + q;
    int lab = labels[row];
    if (lab < NK) continue;
    const float4* e = (const float4*)(embs + (size_t)row*Dn);
    float4 a = e[lane], c = e[lane+64];
    float inv = inv_norm[row];
    a.x*=inv; a.y*=inv; a.z*=inv; a.w*=inv;
    c.x*=inv; c.y*=inv; c.z*=inv; c.w*=inv;
    for (int i = 0; i < nvalid; i++){
      const float4* bb = (const float4*)bnorm[i];
      float s = d4f(a, bb[lane]) + d4f(c, bb[lane+64]);
      s = wred(s);
      if (lane == 0 && s > DELTA_T){
        wlc[wid][i]++;
        float nv = s; int ni = q;
        #pragma unroll
        for (int j = 0; j < MK; j++){
          float cv = wlv[wid][i][j]; int ci = wli[wid][i][j];
          bool better = (nv > cv) || (nv == cv && ni < ci);
          if (better){ wlv[wid][i][j] = nv; wli[wid][i][j] = ni; nv = cv; ni = ci; }
        }
      }
    }
  }
  __syncthreads();
  if (tid < nvalid){
    int i = tid;
    int total = wlc[0][i] + wlc[1][i] + wlc[2][i] + wlc[3][i];
    int cc = total < MK ? total : MK;
    mcnt[i] = cc;
    if (cc > 0){
      int p[4] = {0,0,0,0};
      for (int s = 0; s < cc; s++){
        int bw = -1; float bv = 0.f; int bi = 0;
        for (int wv = 0; wv < 4; wv++){
          int lim = wlc[wv][i] < MK ? wlc[wv][i] : MK;
          if (p[wv] < lim){
            float vv = wlv[wv][i][p[wv]]; int ix = wli[wv][i][p[wv]];
            if (bw < 0 || vv > bv || (vv == bv && ix < bi)){ bw = wv; bv = vv; bi = ix; }
          }
        }
        msel[i][s] = bi; p[bw]++;
      }
      atomicAdd(&sgany, 1);
    }
  }
  __syncthreads();
  if (sgany == 0) return;
  for (int t = tid; t < nvalid*128; t += 256){
    int i = t >> 7, dd = t & 127;
    int cc = mcnt[i];
    float4 s = ((float4*)braw[i])[dd];
    for (int n = 0; n < cc; n++){
      int q = msel[i][n];
      float4 v = ((const float4*)(embs + ((size_t)b*Qn + q)*Dn))[dd];
      s.x += v.x; s.y += v.y; s.z += v.z; s.w += v.w;
    }
    float sc = 1.0f / (1.0f + (float)cc);
    s.x*=sc; s.y*=sc; s.z*=sc; s.w*=sc;
    ((float4*)gb[i])[dd] = s;
  }
  __syncthreads();
  for (int t = tid; t < nvalid*Cn; t += 256){
    int i = t / Cn, cI = t - i*Cn;
    if (mcnt[i] == 0) continue;
    const float4* g = (const float4*)gb[i];
    const float4* wrow = (const float4*)(cls_w + (size_t)cI*Dn);
    float acc = 0.f;
    for (int dd = 0; dd < 128; dd++) acc += d4f(g[dd], wrow[dd]);
    logitsL[i][cI] = acc + cls_b[cI];
  }
  __syncthreads();
  if (tid < nvalid && mcnt[tid] > 0){
    int i = tid;
    float m = -INFINITY;
    for (int cI = 0; cI < Cn; cI++) m = fmaxf(m, logitsL[i][cI]);
    float se = 0.f;
    for (int cI = 0; cI < Cn; cI++) se += expf(logitsL[i][cI] - m);
    float ce = (m + logf(se)) - logitsL[i][Cn-1];
    atomicAdd(sul_sum, ce);
    atomicAdd(n_sg, 1);
  }
}

__global__ __launch_bounds__(256) void k_final(const int* __restrict__ labels,
    const float* __restrict__ pos_exp, const float* __restrict__ col_sum,
    const float* __restrict__ pos_sum, const float* __restrict__ pneg,
    const float* __restrict__ sul_sum, const int* __restrict__ n_sg,
    float* __restrict__ out){
  __shared__ float E[Cn];
  __shared__ float redL[256], redC[256];
  int tid = threadIdx.x;
  for (int i = tid; i < Cn; i += 256) E[i] = pneg[i] + col_sum[i] - pos_sum[i];
  __syncthreads();
  float part = 0.f, cntm = 0.f;
  for (int row = tid; row < NROWS; row += 256){
    int lab = labels[row];
    if (lab < NK){
      float pe = pos_exp[row];
      float ratio = pe / (pe + E[lab] + 1e-8f);
      part += -logf(ratio);
      cntm += 1.f;
    }
  }
  redL[tid] = part; redC[tid] = cntm;
  __syncthreads();
  for (int s = 128; s; s >>= 1){
    if (tid < s){ redL[tid] += redL[tid+s]; redC[tid] += redC[tid+s]; }
    __syncthreads();
  }
  if (tid == 0){
    float cm = redC[0];
    out[1] = (cm > 0.f) ? redL[0] / fmaxf(cm, 1.f) : 0.f;
    int ns = *n_sg;
    out[0] = (ns > 0) ? (*sul_sum) / (float)ns : 0.f;
  }
}

extern "C" void kernel_launch(void* const* d_in, const int* in_sizes, int n_in,
                              void* d_out, int out_size, void* d_ws, size_t ws_size,
                              hipStream_t stream){
  const float* embs   = (const float*)d_in[0];
  const float* protos = (const float*)d_in[1];
  const float* cls_w  = (const float*)d_in[2];
  const float* cls_b  = (const float*)d_in[3];
  const int*   labels = (const int*)d_in[4];
  float* out = (float*)d_out;

  float* w = (float*)d_ws;
  float* inv_norm = w;                            // 64000
  float* dist     = w + 64000;                    // 64000
  float* pos_exp  = w + 128000;                   // 64000
  float* proton   = w + 192000;                   // 41472
  float* col_sum  = w + 233472;                   // 81
  float* pos_sum  = w + 233553;                   // 81
  float* pneg     = w + 233634;                   // 81
  float* sul_sum  = w + 233715;                   // 1
  int*   n_sg     = (int*)(w + 233716);           // 1
  int*   cand_cnt = (int*)(w + 233717);           // 1
  float* cecL     = w + 233718;                   // 1
  float* cecC     = w + 233719;                   // 1
  int*   topi     = (int*)(w + 233720);           // 25600
  int*   nmatch   = (int*)(w + 259320);           // 5120
  int*   bd_row   = (int*)(w + 264440);           // 28672
  int*   cand     = (int*)(w + 293112);           // CAND_CAP = 65024
  float* proto_sq = w + 293112 + CAND_CAP;        // 81 (carved from cand tail)
  unsigned short* protonb = (unsigned short*)(w + 358648); // 96*512 bf16 (permuted)
  unsigned short* embn    = (unsigned short*)(w + 383224); // 64000*512 bf16 (permuted)
  const size_t NEED = (size_t)(383224 + 16384000) * 4;
  const int big = (ws_size >= NEED) ? 1 : 0;

  hipMemsetAsync(col_sum, 0, 248*sizeof(float), stream);

  hipLaunchKernelGGL(k_proto, dim3(96),       dim3(256), 0, stream, protos, proton, protonb, proto_sq, big);
  hipLaunchKernelGGL(k_row,   dim3(NROWS/16), dim3(256), 0, stream, embs, protos, proto_sq, labels, inv_norm, dist, embn, big);
  hipLaunchKernelGGL(k_top5,  dim3(NBK/4),    dim3(256), 0, stream, labels, dist, topi, nmatch, bd_row, big);
  hipLaunchKernelGGL(k_pneg,  dim3(Cn),       dim3(256), 0, stream, proton, pneg);
  if (big){
    hipLaunchKernelGGL(k_cec_mfma, dim3(1000),     dim3(256), 0, stream, embn, protonb, labels, pos_exp, col_sum, pos_sum);
    hipLaunchKernelGGL(k_sim,      dim3(64, 2, 4), dim3(256), 0, stream, embn, bd_row, labels, cand, cand_cnt);
    hipLaunchKernelGGL(k_sel,      dim3(NBK/256),  dim3(256), 0, stream, embs, inv_norm, labels, topi, nmatch, cand, cand_cnt, cls_w, cls_b, sul_sum, n_sg);
    hipLaunchKernelGGL(k_cecsum,   dim3(125),      dim3(256), 0, stream, labels, pos_exp, col_sum, pos_sum, pneg, cecL, cecC);
    hipLaunchKernelGGL(k_out,      dim3(1),        dim3(64),  0, stream, cecL, cecC, sul_sum, n_sg, out);
  } else {
    hipLaunchKernelGGL(k_cec,   dim3(NROWS/TRK), dim3(256), 0, stream, embs, labels, inv_norm, proton, pos_exp, col_sum, pos_sum);
    hipLaunchKernelGGL(k_sul,   dim3(NBK),       dim3(256), 0, stream, embs, inv_norm, labels, topi, nmatch, cls_w, cls_b, sul_sum, n_sg);
    hipLaunchKernelGGL(k_final, dim3(1),         dim3(256), 0, stream, labels, pos_exp, col_sum, pos_sum, pneg, sul_sum, n_sg, out);
  }
}

// Round 12
// 333.988 us; speedup vs baseline: 1.0639x; 1.0639x over previous
//
#include <hip/hip_runtime.h>
#include <math.h>

#define Bn 64
#define Qn 1000
#define Dn 512
#define Cn 81
#define NK 80
#define KB 5
#define MK 5
#define DELTA_T 0.6f
#define FILT_T 0.55f
#define INV_TAU 10.0f
#define NROWS (Bn*Qn)
#define NBK (Bn*NK)
#define NBD 448
#define CAND_CAP 65024

typedef short bf16x8 __attribute__((ext_vector_type(8)));
typedef float f32x4v __attribute__((ext_vector_type(4)));

// Permuted bf16 layout: row r, chunk (s in 0..15, quad in 0..3) holding
// d = quad*8 + s*32 .. +8  lives at elem offset (r>>4)*8192 + s*512 + ((quad*16)+(r&15))*8.
// A wave's MFMA fragment load (16-row tile, all quads, fixed s) is a contiguous 1KB load.

__device__ inline float d4f(const float4 a, const float4 b){
  return a.x*b.x + a.y*b.y + a.z*b.z + a.w*b.w;
}
__device__ inline float wred(float v){
  #pragma unroll
  for (int o = 32; o; o >>= 1) v += __shfl_xor(v, o, 64);
  return v;
}
__device__ inline int wredi(int v){
  #pragma unroll
  for (int o = 32; o; o >>= 1) v += __shfl_xor(v, o, 64);
  return v;
}
__device__ inline unsigned short f2bf(float x){
  union{float f; unsigned u;} v; v.f = x;
  unsigned r = v.u + 0x7fff + ((v.u >> 16) & 1);
  return (unsigned short)(r >> 16);
}
__device__ inline float dot512(const float* __restrict__ a, const float* __restrict__ b){
  const float4* A = (const float4*)a;
  const float4* B = (const float4*)b;
  float s = 0.f;
  for (int i = 0; i < 128; i++) s += d4f(A[i], B[i]);
  return s;
}

// K0: block per proto row. proton fp32; protonb bf16 PERMUTED (rows 81..95 zeroed); proto_sq = ||p_c||^2.
__global__ __launch_bounds__(256) void k_proto(const float* __restrict__ protos,
    float* __restrict__ proton, unsigned short* __restrict__ protonb,
    float* __restrict__ proto_sq, int write_pb){
  int c = blockIdx.x, tid = threadIdx.x;
  int sP = tid >> 4;
  int quadP = (tid & 15) >> 2;
  int offP = (2*tid) & 7;
  size_t pb = (size_t)(c >> 4)*8192 + (size_t)sP*512 + (size_t)(quadP*16 + (c & 15))*8 + offP;
  if (c >= Cn){
    if (write_pb) *(unsigned int*)(protonb + pb) = 0u;
    return;
  }
  __shared__ float accw[4];
  float2 x = ((const float2*)(protos + (size_t)c*Dn))[tid];
  float ss = wred(x.x*x.x + x.y*x.y);
  int wid = tid >> 6, lane = tid & 63;
  if (lane == 0) accw[wid] = ss;
  __syncthreads();
  float s = accw[0] + accw[1] + accw[2] + accw[3];
  float inv = 1.0f / fmaxf(sqrtf(s), 1e-12f);
  float2 y; y.x = x.x*inv; y.y = x.y*inv;
  ((float2*)(proton + (size_t)c*Dn))[tid] = y;
  if (tid == 0) proto_sq[c] = s;
  if (write_pb){
    unsigned int pk = ((unsigned)f2bf(y.y) << 16) | (unsigned)f2bf(y.x);
    *(unsigned int*)(protonb + pb) = pk;
  }
}

// K1: block = one 16-row embn tile; swizzled LDS transpose; coalesced tile write.
__global__ __launch_bounds__(256) void k_row(const float* __restrict__ embs,
    const float* __restrict__ protos, const float* __restrict__ proto_sq,
    const int* __restrict__ labels, float* __restrict__ inv_norm,
    float* __restrict__ dist, unsigned short* __restrict__ embn, int write_e){
  __shared__ bf16x8 T[1024];   // 16 KB
  int tid = threadIdx.x, w = tid >> 6, lane = tid & 63;
  int r0 = blockIdx.x*16;
  char* base = (char*)T;
  #pragma unroll
  for (int i = 0; i < 4; i++){
    int j = w*4 + i;
    int row = r0 + j;
    const float4* e = (const float4*)(embs + (size_t)row*Dn);
    float4 a = e[lane], b = e[lane+64];
    int lab = labels[row];                      // wave-uniform
    float e2 = wred(d4f(a,a) + d4f(b,b));
    float ep = 0.f;
    if (lab < NK){
      const float4* p = (const float4*)(protos + (size_t)lab*Dn);
      ep = wred(d4f(a, p[lane]) + d4f(b, p[lane+64]));
    }
    float inv = 1.0f / fmaxf(sqrtf(e2), 1e-12f);
    if (lane == 0){
      inv_norm[row] = inv;
      dist[row] = (lab < NK) ? sqrtf(fmaxf(e2 - 2.f*ep + proto_sq[lab], 1e-12f)) : -INFINITY;
    }
    if (write_e){
      ushort4 ua; ua.x=f2bf(a.x*inv); ua.y=f2bf(a.y*inv); ua.z=f2bf(a.z*inv); ua.w=f2bf(a.w*inv);
      ushort4 ub; ub.x=f2bf(b.x*inv); ub.y=f2bf(b.y*inv); ub.z=f2bf(b.z*inv); ub.w=f2bf(b.w*inv);
      int g  = lane >> 1;
      int off = (lane & 1) * 8;
      *(ushort4*)(base + g*256       + (((j + g)      & 15) << 4) + off) = ua;
      *(ushort4*)(base + (g+32)*256  + (((j + g + 32) & 15) << 4) + off) = ub;
    }
  }
  if (write_e){
    __syncthreads();
    unsigned short* out = embn + (size_t)(r0 >> 4)*8192;
    #pragma unroll
    for (int pp = 0; pp < 4; pp++){
      int c = tid + pp*256;
      int g = c >> 4, j = c & 15;
      bf16x8 v = *(bf16x8*)(base + g*256 + (((j + g) & 15) << 4));
      *(bf16x8*)(out + (size_t)c*8) = v;
    }
  }
}

// K3 v2: wave per (b,k); lane scans 2 consecutive q via int2/float2 (8 iters).
// Selection order-independent (index tie-break). Invalid slots -> bd_row = -1.
__global__ __launch_bounds__(256) void k_top5(const int* __restrict__ labels,
    const float* __restrict__ dist, int* __restrict__ topi, int* __restrict__ nmatch,
    int* __restrict__ bd_row, int write_bd){
  int wid = threadIdx.x >> 6, lane = threadIdx.x & 63;
  int gid = blockIdx.x*4 + wid;
  if (gid >= NBK) return;
  int b = gid / NK, k = gid - b*NK;
  const int*   lrow = labels + b*Qn;
  const float* drow = dist   + b*Qn;
  float v[KB]; int id[KB];
  #pragma unroll
  for (int j = 0; j < KB; j++){ v[j] = -INFINITY; id[j] = 0x7fffffff; }
  int cnt = 0;
  #pragma unroll
  for (int it = 0; it < 8; it++){
    int q = it*128 + lane*2;
    if (q >= Qn) continue;
    int2   l2 = *(const int2*)(lrow + q);
    float2 d2 = *(const float2*)(drow + q);
    #pragma unroll
    for (int u = 0; u < 2; u++){
      int qq = q + u;
      int lv = u ? l2.y : l2.x;
      float dv = u ? d2.y : d2.x;
      if (qq < Qn && lv == k){
        cnt++;
        float nv = dv; int ni = qq;
        #pragma unroll
        for (int j = 0; j < KB; j++){
          bool better = (nv > v[j]) || (nv == v[j] && ni < id[j]);
          if (better){
            float tv = v[j]; v[j] = nv; nv = tv;
            int ti = id[j]; id[j] = ni; ni = ti;
          }
        }
      }
    }
  }
  cnt = wredi(cnt);
  int p = 0;
  int outi[KB];
  #pragma unroll
  for (int s = 0; s < KB; s++){
    float bv = (p < KB) ? v[p] : -INFINITY;
    int   bi = (p < KB) ? id[p] : 0x7fffffff;
    int   bl = lane;
    #pragma unroll
    for (int o = 32; o; o >>= 1){
      float ov = __shfl_xor(bv, o, 64);
      int   oi = __shfl_xor(bi, o, 64);
      int   ol = __shfl_xor(bl, o, 64);
      if (ov > bv || (ov == bv && oi < bi)){ bv = ov; bi = oi; bl = ol; }
    }
    if (bl == lane) p++;
    outi[s] = (bv != -INFINITY) ? bi : 0;
  }
  if (lane == 0){
    #pragma unroll
    for (int j = 0; j < KB; j++) topi[gid*KB + j] = outi[j];
    nmatch[gid] = cnt;
    if (write_bd){
      int cv = cnt < KB ? cnt : KB;
      #pragma unroll
      for (int j = 0; j < KB; j++)
        bd_row[b*NBD + k*KB + j] = (j < cv) ? (b*Qn + outi[j]) : -1;
      if (k < NBD - NK*KB) bd_row[b*NBD + NK*KB + k] = -1;
    }
  }
}

// K2b v2: CEC via MFMA, M=32 per wave (two 16-row tiles share the B stream).
// 12 MFMAs per 8 frag loads; grid 500 blocks (128 rows/block).
__global__ __launch_bounds__(256) void k_cec_mfma(
    const unsigned short* __restrict__ embn, const unsigned short* __restrict__ protonb,
    const int* __restrict__ labels, float* __restrict__ pos_exp,
    float* __restrict__ col_sum, float* __restrict__ pos_sum){
  __shared__ float colL[96], posL[96];
  int tid = threadIdx.x, w = tid >> 6, l = tid & 63;
  for (int i = tid; i < 96; i += 256){ colL[i] = 0.f; posL[i] = 0.f; }
  __syncthreads();
  int quad = l >> 4, m15 = l & 15;
  int r0 = blockIdx.x*128 + w*32;
  const unsigned short* abase0 = embn + (size_t)(r0 >> 4)*8192 + (size_t)l*8;
  const unsigned short* abase1 = abase0 + 8192;
  const unsigned short* bbase = protonb + (size_t)l*8;
  f32x4v acc[2][6];
  #pragma unroll
  for (int t = 0; t < 2; t++)
    #pragma unroll
    for (int f = 0; f < 6; f++) acc[t][f] = (f32x4v){0.f,0.f,0.f,0.f};
  for (int s = 0; s < 16; s++){
    bf16x8 a0 = *(const bf16x8*)(abase0 + s*512);
    bf16x8 a1 = *(const bf16x8*)(abase1 + s*512);
    #pragma unroll
    for (int f = 0; f < 6; f++){
      bf16x8 bb = *(const bf16x8*)(bbase + (size_t)f*8192 + s*512);
      acc[0][f] = __builtin_amdgcn_mfma_f32_16x16x32_bf16(a0, bb, acc[0][f], 0, 0, 0);
      acc[1][f] = __builtin_amdgcn_mfma_f32_16x16x32_bf16(a1, bb, acc[1][f], 0, 0, 0);
    }
  }
  int labs[2][4];
  #pragma unroll
  for (int t = 0; t < 2; t++)
    #pragma unroll
    for (int r = 0; r < 4; r++) labs[t][r] = labels[r0 + t*16 + quad*4 + r];
  #pragma unroll
  for (int f = 0; f < 6; f++){
    int c = f*16 + m15;
    float colp = 0.f;
    #pragma unroll
    for (int t = 0; t < 2; t++){
      #pragma unroll
      for (int r = 0; r < 4; r++){
        if (labs[t][r] < NK && c < Cn){
          float es = expf(acc[t][f][r] * INV_TAU);
          colp += es;
          if (labs[t][r] == c){
            pos_exp[r0 + t*16 + quad*4 + r] = es;
            atomicAdd(&posL[c], es);
          }
        }
      }
    }
    colp += __shfl_xor(colp, 16, 64);
    colp += __shfl_xor(colp, 32, 64);
    if (quad == 0 && c < Cn && colp != 0.f) atomicAdd(&colL[c], colp);
  }
  __syncthreads();
  for (int i = tid; i < Cn; i += 256){
    if (colL[i] != 0.f) atomicAdd(&col_sum[i], colL[i]);
    if (posL[i] != 0.f) atomicAdd(&pos_sum[i], posL[i]);
  }
}

// K4b: LDS dbuf A-tile pipeline; each wave holds TWO B-frag sets (32 n rows).
// Grid (b, half, nt) = (64,2,4); block covers 128 n.
__global__ __launch_bounds__(256) void k_sim(
    const unsigned short* __restrict__ embn, const int* __restrict__ bd_row,
    const int* __restrict__ labels, int* __restrict__ cand, int* __restrict__ cand_cnt){
  __shared__ bf16x8 At[2][1024];
  int b = blockIdx.x, half = blockIdx.y, nt = blockIdx.z;
  int tid = threadIdx.x, w = tid >> 6, l = tid & 63;
  int quad = l >> 4, m15 = l & 15;

  int n0 = nt*128 + w*16 + m15;
  int n1 = n0 + 64;
  int i0 = n0 < NBD ? n0 : NBD-1;
  int i1 = n1 < NBD ? n1 : NBD-1;
  int br0 = bd_row[b*NBD + i0];
  int br1 = bd_row[b*NBD + i1];
  int valid0 = (br0 >= 0) && (n0 < NK*KB);
  int valid1 = (br1 >= 0) && (n1 < NK*KB);
  int rowb0 = valid0 ? br0 : b*Qn;
  int rowb1 = valid1 ? br1 : b*Qn;
  const unsigned short* bp0 = embn + (size_t)(rowb0 >> 4)*8192 + (size_t)(rowb0 & 15)*8 + quad*128;
  const unsigned short* bp1 = embn + (size_t)(rowb1 >> 4)*8192 + (size_t)(rowb1 & 15)*8 + quad*128;
  bf16x8 bfr0[16], bfr1[16];
  #pragma unroll
  for (int s = 0; s < 16; s++){
    bfr0[s] = *(const bf16x8*)(bp0 + s*512);
    bfr1[s] = *(const bf16x8*)(bp1 + s*512);
  }

  const int qlo = half*500, qhi = qlo + 500;
  const int bq = b*Qn;
  const int qstart = half ? 488 : 0;

  int jloc = tid & 15, quadp = (tid >> 4) & 3;

  {
    int g = bq + qstart + jloc;
    size_t ro = (size_t)(g >> 4)*8192 + (size_t)(quadp*16 + (g & 15))*8;
    #pragma unroll
    for (int pp = 0; pp < 4; pp++)
      At[0][tid + pp*256] = *(const bf16x8*)(embn + ro + (size_t)(w + pp*4)*512);
  }
  __syncthreads();

  for (int it = 0; it < 32; it++){
    int buf = it & 1;
    bf16x8 pre[4];
    if (it < 31){
      int g = bq + qstart + (it+1)*16 + jloc;
      size_t ro = (size_t)(g >> 4)*8192 + (size_t)(quadp*16 + (g & 15))*8;
      #pragma unroll
      for (int pp = 0; pp < 4; pp++)
        pre[pp] = *(const bf16x8*)(embn + ro + (size_t)(w + pp*4)*512);
    }
    f32x4v a0 = (f32x4v){0.f,0.f,0.f,0.f};
    f32x4v a1 = (f32x4v){0.f,0.f,0.f,0.f};
    #pragma unroll
    for (int s = 0; s < 16; s++){
      bf16x8 av = At[buf][s*64 + l];
      a0 = __builtin_amdgcn_mfma_f32_16x16x32_bf16(av, bfr0[s], a0, 0, 0, 0);
      a1 = __builtin_amdgcn_mfma_f32_16x16x32_bf16(av, bfr1[s], a1, 0, 0, 0);
    }
    int qb = qstart + it*16 + quad*4;
    #pragma unroll
    for (int j = 0; j < 2; j++){
      f32x4v av = j ? a1 : a0;
      int vj = j ? valid1 : valid0;
      int nj = j ? n1 : n0;
      #pragma unroll
      for (int r = 0; r < 4; r++){
        float sv = av[r];
        int q = qb + r;
        if (vj && sv > FILT_T && q >= qlo && q < qhi){
          if (labels[bq + q] >= NK){
            int idx = atomicAdd(cand_cnt, 1);
            if (idx < CAND_CAP) cand[idx] = ((b*NBD + nj) << 10) | q;
          }
        }
      }
    }
    __syncthreads();
    if (it < 31){
      #pragma unroll
      for (int pp = 0; pp < 4; pp++)
        At[buf^1][tid + pp*256] = pre[pp];
    }
    __syncthreads();
  }
}

// K4c: resolve candidates exactly (rare path).
__global__ __launch_bounds__(256) void k_sel(
    const float* __restrict__ embs, const float* __restrict__ inv_norm,
    const int* __restrict__ labels, const int* __restrict__ topi,
    const int* __restrict__ nmatch, const int* __restrict__ cand,
    const int* __restrict__ cand_cnt, const float* __restrict__ cls_w,
    const float* __restrict__ cls_b, float* __restrict__ sul_sum, int* __restrict__ n_sg){
  int gid = blockIdx.x*256 + threadIdx.x;
  if (gid >= NBK) return;
  int b = gid / NK, k = gid - b*NK;
  int nm = nmatch[gid];
  int nvalid = nm < KB ? nm : KB;
  int nc = *cand_cnt; if (nc > CAND_CAP) nc = CAND_CAP;
  if (nvalid == 0 || nc == 0) return;
  float tv[KB][MK]; int ti[KB][MK]; int tc[KB];
  #pragma unroll
  for (int i = 0; i < KB; i++){
    tc[i] = 0;
    #pragma unroll
    for (int j = 0; j < MK; j++){ tv[i][j] = -INFINITY; ti[i][j] = 0x7fffffff; }
  }
  for (int j = 0; j < nc; j++){
    int code = cand[j];
    int q = code & 1023;
    int t = code >> 10;
    int b2 = t / NBD, n = t - b2*NBD;
    if (b2 != b) continue;
    int k2 = n / KB, i = n - k2*KB;
    if (k2 != k || i >= nvalid) continue;
    int rq = b*Qn + q;
    int rb = b*Qn + topi[gid*KB + i];
    float s = inv_norm[rq]*inv_norm[rb]*dot512(embs + (size_t)rq*Dn, embs + (size_t)rb*Dn);
    if (s > DELTA_T){
      tc[i]++;
      float nv = s; int ni = q;
      #pragma unroll
      for (int jj = 0; jj < MK; jj++){
        float cv = tv[i][jj]; int ci = ti[i][jj];
        bool better = (nv > cv) || (nv == cv && ni < ci);
        if (better){ tv[i][jj] = nv; ti[i][jj] = ni; nv = cv; ni = ci; }
      }
    }
  }
  for (int i = 0; i < nvalid; i++){
    int cc = tc[i] < MK ? tc[i] : MK;
    if (cc == 0) continue;
    int rb = b*Qn + topi[gid*KB + i];
    float sc = 1.0f / (1.0f + (float)cc);
    float m = -INFINITY, ssum = 0.f, lunk = 0.f;
    for (int c = 0; c < Cn; c++){
      const float* wc = cls_w + (size_t)c*Dn;
      float a = dot512(embs + (size_t)rb*Dn, wc);
      for (int nn = 0; nn < cc; nn++)
        a += dot512(embs + (size_t)(b*Qn + ti[i][nn])*Dn, wc);
      float logit = a*sc + cls_b[c];
      if (c == Cn-1) lunk = logit;
      if (logit > m){ ssum = ssum*expf(m - logit) + 1.f; m = logit; }
      else ssum += expf(logit - m);
    }
    float ce = (m + logf(ssum)) - lunk;
    atomicAdd(sul_sum, ce);
    atomicAdd(n_sg, 1);
  }
}

// K5: p_neg — block per class, wave per partner chunk.
__global__ __launch_bounds__(256) void k_pneg(const float* __restrict__ proton,
                                              float* __restrict__ pneg){
  __shared__ float accw[4];
  int c = blockIdx.x;
  int wid = threadIdx.x >> 6, lane = threadIdx.x & 63;
  const float4* crow = (const float4*)(proton + (size_t)c*Dn);
  float4 ca = crow[lane], cb = crow[lane+64];
  float acc = 0.f;
  for (int cp = wid; cp < Cn; cp += 4){
    if (cp == c) continue;
    const float4* prow = (const float4*)(proton + (size_t)cp*Dn);
    float s = wred(d4f(ca, prow[lane]) + d4f(cb, prow[lane+64]));
    acc += expf(s*INV_TAU);
  }
  if (lane == 0) accw[wid] = acc;
  __syncthreads();
  if (threadIdx.x == 0) pneg[c] = accw[0]+accw[1]+accw[2]+accw[3];
}

// K6a: CEC row-loss partial sums (125 blocks x 512 rows).
__global__ __launch_bounds__(256) void k_cecsum(const int* __restrict__ labels,
    const float* __restrict__ pos_exp, const float* __restrict__ col_sum,
    const float* __restrict__ pos_sum, const float* __restrict__ pneg,
    float* __restrict__ cecL, float* __restrict__ cecC){
  __shared__ float E[Cn];
  __shared__ float aw[4], cw[4];
  int tid = threadIdx.x;
  for (int i = tid; i < Cn; i += 256) E[i] = pneg[i] + col_sum[i] - pos_sum[i];
  __syncthreads();
  float part = 0.f; int cm = 0;
  int row0 = blockIdx.x*512;
  #pragma unroll
  for (int rr = 0; rr < 2; rr++){
    int r = row0 + rr*256 + tid;
    int lab = labels[r];
    if (lab < NK){
      float pe = pos_exp[r];
      part += -logf(pe / (pe + E[lab] + 1e-8f));
      cm++;
    }
  }
  part = wred(part); cm = wredi(cm);
  int wid = tid >> 6, lane = tid & 63;
  if (lane == 0){ aw[wid] = part; cw[wid] = (float)cm; }
  __syncthreads();
  if (tid == 0){
    atomicAdd(cecL, aw[0]+aw[1]+aw[2]+aw[3]);
    atomicAdd(cecC, cw[0]+cw[1]+cw[2]+cw[3]);
  }
}

// K6b: finalize
__global__ void k_out(const float* __restrict__ cecL, const float* __restrict__ cecC,
    const float* __restrict__ sul_sum, const int* __restrict__ n_sg,
    float* __restrict__ out){
  if (threadIdx.x == 0){
    float cm = *cecC;
    out[1] = (cm > 0.f) ? (*cecL) / fmaxf(cm, 1.f) : 0.f;
    int ns = *n_sg;
    out[0] = (ns > 0) ? (*sul_sum) / (float)ns : 0.f;
  }
}

// ---------------- fallback (small-ws) kernels ----------------
#define TRK 25
#define TSTR 516
__global__ __launch_bounds__(256) void k_cec(const float* __restrict__ embs,
    const int* __restrict__ labels, const float* __restrict__ inv_norm,
    const float* __restrict__ proton, float* __restrict__ pos_exp,
    float* __restrict__ col_sum, float* __restrict__ pos_sum){
  __shared__ float tile[TRK*TSTR];
  __shared__ float colL[Cn], posL[Cn];
  int tid = threadIdx.x;
  int r0 = blockIdx.x * TRK;
  for (int i = tid; i < Cn; i += 256){ colL[i] = 0.f; posL[i] = 0.f; }
  for (int idx = tid; idx < TRK*128; idx += 256){
    int r = idx >> 7, dd = idx & 127;
    float inv = inv_norm[r0 + r];
    float4 v = ((const float4*)(embs + (size_t)(r0+r)*Dn))[dd];
    v.x*=inv; v.y*=inv; v.z*=inv; v.w*=inv;
    ((float4*)(tile + r*TSTR))[dd] = v;
  }
  __syncthreads();
  for (int item = tid; item < 27*TRK; item += 256){
    int g = item / TRK, r = item - g*TRK;
    int row = r0 + r;
    int lab = labels[row];
    if (lab >= NK) continue;
    int c0 = g*3;
    const float4* t  = (const float4*)(tile + r*TSTR);
    const float4* pa = (const float4*)(proton + (size_t)c0*Dn);
    const float4* pb = (const float4*)(proton + (size_t)(c0+1)*Dn);
    const float4* pc = (const float4*)(proton + (size_t)(c0+2)*Dn);
    float a0=0.f, a1=0.f, a2=0.f;
    for (int dd = 0; dd < 128; dd++){
      float4 v = t[dd];
      a0 += d4f(v, pa[dd]);
      a1 += d4f(v, pb[dd]);
      a2 += d4f(v, pc[dd]);
    }
    float es0 = expf(a0*INV_TAU), es1 = expf(a1*INV_TAU), es2 = expf(a2*INV_TAU);
    atomicAdd(&colL[c0+0], es0);
    atomicAdd(&colL[c0+1], es1);
    atomicAdd(&colL[c0+2], es2);
    if (c0+0 == lab){ pos_exp[row] = es0; atomicAdd(&posL[lab], es0); }
    if (c0+1 == lab){ pos_exp[row] = es1; atomicAdd(&posL[lab], es1); }
    if (c0+2 == lab){ pos_exp[row] = es2; atomicAdd(&posL[lab], es2); }
  }
  __syncthreads();
  for (int i = tid; i < Cn; i += 256){
    if (colL[i] != 0.f) atomicAdd(&col_sum[i], colL[i]);
    if (posL[i] != 0.f) atomicAdd(&pos_sum[i], posL[i]);
  }
}

__global__ __launch_bounds__(256) void k_sul(
    const float* __restrict__ embs, const float* __restrict__ inv_norm,
    const int* __restrict__ labels, const int* __restrict__ topi,
    const int* __restrict__ nmatch, const float* __restrict__ cls_w,
    const float* __restrict__ cls_b, float* __restrict__ sul_sum,
    int* __restrict__ n_sg){
  __shared__ float bnorm[KB][Dn];
  __shared__ float braw[KB][Dn];
  __shared__ float gb[KB][Dn];
  __shared__ float logitsL[KB][Cn];
  __shared__ float wlv[4][KB][MK];
  __shared__ int   wli[4][KB][MK];
  __shared__ int   wlc[4][KB];
  __shared__ int   msel[KB][MK];
  __shared__ int   mcnt[KB];
  __shared__ int   sgany;
  int gid = blockIdx.x;
  int nm = nmatch[gid];
  int nvalid = nm < KB ? nm : KB;
  if (nvalid == 0) return;
  int b = gid / NK;
  int tid = threadIdx.x, wid = tid >> 6, lane = tid & 63;
  for (int t = tid; t < nvalid*128; t += 256){
    int i = t >> 7, dd = t & 127;
    int q = topi[gid*KB + i];
    size_t row = (size_t)b*Qn + q;
    float4 v = ((const float4*)(embs + row*Dn))[dd];
    ((float4*)braw[i])[dd] = v;
    float inv = inv_norm[row];
    v.x*=inv; v.y*=inv; v.z*=inv; v.w*=inv;
    ((float4*)bnorm[i])[dd] = v;
  }
  if (tid < 4*KB) ((int*)wlc)[tid] = 0;
  if (tid < 4*KB*MK){ ((float*)wlv)[tid] = -INFINITY; ((int*)wli)[tid] = 0x7fffffff; }
  if (tid == 0) sgany = 0;
  __syncthreads();
  for (int q = wid; q < Qn; q += 4){
    int row = b*Qn + q;
    int lab = labels[row];
    if (lab < NK) continue;
    const float4* e = (const float4*)(embs + (size_t)row*Dn);
    float4 a = e[lane], c = e[lane+64];
    float inv = inv_norm[row];
    a.x*=inv; a.y*=inv; a.z*=inv; a.w*=inv;
    c.x*=inv; c.y*=inv; c.z*=inv; c.w*=inv;
    for (int i = 0; i < nvalid; i++){
      const float4* bb = (const float4*)bnorm[i];
      float s = d4f(a, bb[lane]) + d4f(c, bb[lane+64]);
      s = wred(s);
      if (lane == 0 && s > DELTA_T){
        wlc[wid][i]++;
        float nv = s; int ni = q;
        #pragma unroll
        for (int j = 0; j < MK; j++){
          float cv = wlv[wid][i][j]; int ci = wli[wid][i][j];
          bool better = (nv > cv) || (nv == cv && ni < ci);
          if (better){ wlv[wid][i][j] = nv; wli[wid][i][j] = ni; nv = cv; ni = ci; }
        }
      }
    }
  }
  __syncthreads();
  if (tid < nvalid){
    int i = tid;
    int total = wlc[0][i] + wlc[1][i] + wlc[2][i] + wlc[3][i];
    int cc = total < MK ? total : MK;
    mcnt[i] = cc;
    if (cc > 0){
      int p[4] = {0,0,0,0};
      for (int s = 0; s < cc; s++){
        int bw = -1; float bv = 0.f; int bi = 0;
        for (int wv = 0; wv < 4; wv++){
          int lim = wlc[wv][i] < MK ? wlc[wv][i] : MK;
          if (p[wv] < lim){
            float vv = wlv[wv][i][p[wv]]; int ix = wli[wv][i][p[wv]];
            if (bw < 0 || vv > bv || (vv == bv && ix < bi)){ bw = wv; bv = vv; bi = ix; }
          }
        }
        msel[i][s] = bi; p[bw]++;
      }
      atomicAdd(&sgany, 1);
    }
  }
  __syncthreads();
  if (sgany == 0) return;
  for (int t = tid; t < nvalid*128; t += 256){
    int i = t >> 7, dd = t & 127;
    int cc = mcnt[i];
    float4 s = ((float4*)braw[i])[dd];
    for (int n = 0; n < cc; n++){
      int q = msel[i][n];
      float4 v = ((const float4*)(embs + ((size_t)b*Qn + q)*Dn))[dd];
      s.x += v.x; s.y += v.y; s.z += v.z; s.w += v.w;
    }
    float sc = 1.0f / (1.0f + (float)cc);
    s.x*=sc; s.y*=sc; s.z*=sc; s.w*=sc;
    ((float4*)gb[i])[dd] = s;
  }
  __syncthreads();
  for (int t = tid; t < nvalid*Cn; t += 256){
    int i = t / Cn, cI = t - i*Cn;
    if (mcnt[i] == 0) continue;
    const float4* g = (const float4*)gb[i];
    const float4* wrow = (const float4*)(cls_w + (size_t)cI*Dn);
    float acc = 0.f;
    for (int dd = 0; dd < 128; dd++) acc += d4f(g[dd], wrow[dd]);
    logitsL[i][cI] = acc + cls_b[cI];
  }
  __syncthreads();
  if (tid < nvalid && mcnt[tid] > 0){
    int i = tid;
    float m = -INFINITY;
    for (int cI = 0; cI < Cn; cI++) m = fmaxf(m, logitsL[i][cI]);
    float se = 0.f;
    for (int cI = 0; cI < Cn; cI++) se += expf(logitsL[i][cI] - m);
    float ce = (m + logf(se)) - logitsL[i][Cn-1];
    atomicAdd(sul_sum, ce);
    atomicAdd(n_sg, 1);
  }
}

__global__ __launch_bounds__(256) void k_final(const int* __restrict__ labels,
    const float* __restrict__ pos_exp, const float* __restrict__ col_sum,
    const float* __restrict__ pos_sum, const float* __restrict__ pneg,
    const float* __restrict__ sul_sum, const int* __restrict__ n_sg,
    float* __restrict__ out){
  __shared__ float E[Cn];
  __shared__ float redL[256], redC[256];
  int tid = threadIdx.x;
  for (int i = tid; i < Cn; i += 256) E[i] = pneg[i] + col_sum[i] - pos_sum[i];
  __syncthreads();
  float part = 0.f, cntm = 0.f;
  for (int row = tid; row < NROWS; row += 256){
    int lab = labels[row];
    if (lab < NK){
      float pe = pos_exp[row];
      float ratio = pe / (pe + E[lab] + 1e-8f);
      part += -logf(ratio);
      cntm += 1.f;
    }
  }
  redL[tid] = part; redC[tid] = cntm;
  __syncthreads();
  for (int s = 128; s; s >>= 1){
    if (tid < s){ redL[tid] += redL[tid+s]; redC[tid] += redC[tid+s]; }
    __syncthreads();
  }
  if (tid == 0){
    float cm = redC[0];
    out[1] = (cm > 0.f) ? redL[0] / fmaxf(cm, 1.f) : 0.f;
    int ns = *n_sg;
    out[0] = (ns > 0) ? (*sul_sum) / (float)ns : 0.f;
  }
}

extern "C" void kernel_launch(void* const* d_in, const int* in_sizes, int n_in,
                              void* d_out, int out_size, void* d_ws, size_t ws_size,
                              hipStream_t stream){
  const float* embs   = (const float*)d_in[0];
  const float* protos = (const float*)d_in[1];
  const float* cls_w  = (const float*)d_in[2];
  const float* cls_b  = (const float*)d_in[3];
  const int*   labels = (const int*)d_in[4];
  float* out = (float*)d_out;

  float* w = (float*)d_ws;
  float* inv_norm = w;                            // 64000
  float* dist     = w + 64000;                    // 64000
  float* pos_exp  = w + 128000;                   // 64000
  float* proton   = w + 192000;                   // 41472
  float* col_sum  = w + 233472;                   // 81
  float* pos_sum  = w + 233553;                   // 81
  float* pneg     = w + 233634;                   // 81
  float* sul_sum  = w + 233715;                   // 1
  int*   n_sg     = (int*)(w + 233716);           // 1
  int*   cand_cnt = (int*)(w + 233717);           // 1
  float* cecL     = w + 233718;                   // 1
  float* cecC     = w + 233719;                   // 1
  int*   topi     = (int*)(w + 233720);           // 25600
  int*   nmatch   = (int*)(w + 259320);           // 5120
  int*   bd_row   = (int*)(w + 264440);           // 28672
  int*   cand     = (int*)(w + 293112);           // CAND_CAP = 65024
  float* proto_sq = w + 293112 + CAND_CAP;        // 81 (carved from cand tail)
  unsigned short* protonb = (unsigned short*)(w + 358648); // 96*512 bf16 (permuted)
  unsigned short* embn    = (unsigned short*)(w + 383224); // 64000*512 bf16 (permuted)
  const size_t NEED = (size_t)(383224 + 16384000) * 4;
  const int big = (ws_size >= NEED) ? 1 : 0;

  hipMemsetAsync(col_sum, 0, 248*sizeof(float), stream);

  hipLaunchKernelGGL(k_proto, dim3(96),       dim3(256), 0, stream, protos, proton, protonb, proto_sq, big);
  hipLaunchKernelGGL(k_row,   dim3(NROWS/16), dim3(256), 0, stream, embs, protos, proto_sq, labels, inv_norm, dist, embn, big);
  hipLaunchKernelGGL(k_top5,  dim3(NBK/4),    dim3(256), 0, stream, labels, dist, topi, nmatch, bd_row, big);
  hipLaunchKernelGGL(k_pneg,  dim3(Cn),       dim3(256), 0, stream, proton, pneg);
  if (big){
    hipLaunchKernelGGL(k_cec_mfma, dim3(500),      dim3(256), 0, stream, embn, protonb, labels, pos_exp, col_sum, pos_sum);
    hipLaunchKernelGGL(k_sim,      dim3(64, 2, 4), dim3(256), 0, stream, embn, bd_row, labels, cand, cand_cnt);
    hipLaunchKernelGGL(k_sel,      dim3(NBK/256),  dim3(256), 0, stream, embs, inv_norm, labels, topi, nmatch, cand, cand_cnt, cls_w, cls_b, sul_sum, n_sg);
    hipLaunchKernelGGL(k_cecsum,   dim3(125),      dim3(256), 0, stream, labels, pos_exp, col_sum, pos_sum, pneg, cecL, cecC);
    hipLaunchKernelGGL(k_out,      dim3(1),        dim3(64),  0, stream, cecL, cecC, sul_sum, n_sg, out);
  } else {
    hipLaunchKernelGGL(k_cec,   dim3(NROWS/TRK), dim3(256), 0, stream, embs, labels, inv_norm, proton, pos_exp, col_sum, pos_sum);
    hipLaunchKernelGGL(k_sul,   dim3(NBK),       dim3(256), 0, stream, embs, inv_norm, labels, topi, nmatch, cls_w, cls_b, sul_sum, n_sg);
    hipLaunchKernelGGL(k_final, dim3(1),         dim3(256), 0, stream, labels, pos_exp, col_sum, pos_sum, pneg, sul_sum, n_sg, out);
  }
}